// Round 1
// baseline (4183.310 us; speedup 1.0000x reference)
//
#include <hip/hip_runtime.h>
#include <hip/hip_bf16.h>
#include <math.h>

using f4 = __attribute__((ext_vector_type(4))) float;

constexpr int cV = 32000, cC = 1024;
constexpr int cNH = 16, cNKV = 8, cHD = 64;
constexpr int cE = 8, cHID = 2728;
constexpr int cB = 2, cT = 1024, cN = cB * cT;

__device__ inline float dot4(f4 a, f4 b) { return a[0]*b[0] + a[1]*b[1] + a[2]*b[2] + a[3]*b[3]; }

// ---------------- embedding gather ----------------
__global__ void embed_k(const int* __restrict__ idx, const float* __restrict__ wte,
                        float* __restrict__ x)
{
  int n = blockIdx.x, tid = threadIdx.x;
  size_t row = (size_t)idx[n] * cC;
  *(f4*)(x + (size_t)n * cC + tid * 4) = *(const f4*)(wte + row + tid * 4);
}

// ---------------- rmsnorm (one block per row, C=1024) ----------------
__global__ __launch_bounds__(256) void rmsnorm_k(const float* __restrict__ in,
                                                 const float* __restrict__ w,
                                                 float* __restrict__ out)
{
  int n = blockIdx.x, tid = threadIdx.x;
  f4 v = *(const f4*)(in + (size_t)n * cC + tid * 4);
  float s = dot4(v, v);
  #pragma unroll
  for (int off = 32; off; off >>= 1) s += __shfl_xor(s, off);
  __shared__ float red[4];
  if ((tid & 63) == 0) red[tid >> 6] = s;
  __syncthreads();
  float tot = red[0] + red[1] + red[2] + red[3];
  float inv = rsqrtf(tot * (1.0f / cC) + 1e-5f);
  f4 wv = *(const f4*)(w + tid * 4);
  f4 o = v * inv * wv;
  *(f4*)(out + (size_t)n * cC + tid * 4) = o;
}

// ---------------- generic fp32 GEMM, 64x64x16 tiles, 256 thr, 4x4/thread ----
// EPI: 0 store, 1 +=, 2 silu-store, 3 *= (in-place)
// GATH: 0 none; 1 A-row = list[m]>>1, C-row = list[m]; 2 A-row = C-row = list[m]
template<int EPI, int GATH>
__global__ __launch_bounds__(256) void gemm64(
    const float* __restrict__ A, const float* __restrict__ Bm, float* __restrict__ Cmat,
    int M, int Nc, int K, int lda, int ldb, int ldc,
    const int* __restrict__ gidx, const int* __restrict__ gcnt)
{
  int Me = M;
  const int* idxp = nullptr;
  if (GATH) {
    int e = blockIdx.z;
    Me = gcnt[e];
    idxp = gidx + (size_t)e * cN;
    Bm += (size_t)e * K * ldb;         // per-expert weight slab
  }
  int m0 = blockIdx.y * 64;
  if (m0 >= Me) return;
  int n0 = blockIdx.x * 64;

  __shared__ float As[16][68];   // As[k][m]
  __shared__ float Bs[16][68];   // Bs[k][n]

  int tid = threadIdx.x;
  int ty = tid >> 4, tx = tid & 15;

  // A-load mapping: 4 threads per row, each a float4 of K
  int arow = m0 + (tid >> 2);
  int kq = tid & 3;
  bool rv = arow < Me;
  size_t asrc = 0;
  if (rv) {
    int t = GATH ? idxp[arow] : arow;
    asrc = (size_t)((GATH == 1) ? (t >> 1) : t) * lda;
  }
  // B-load mapping: thread -> (k = tid>>4, n-quad = tid&15)
  int bk = tid >> 4;
  int bn = n0 + (tid & 15) * 4;

  float acc[4][4] = {};

  for (int k0 = 0; k0 < K; k0 += 16) {
    f4 av = {0.f, 0.f, 0.f, 0.f};
    int kcol = k0 + kq * 4;
    if (rv) {
      if (kcol + 3 < K) av = *(const f4*)(A + asrc + kcol);
      else {
        #pragma unroll
        for (int j = 0; j < 4; j++) if (kcol + j < K) av[j] = A[asrc + kcol + j];
      }
    }
    f4 bv = {0.f, 0.f, 0.f, 0.f};
    if (k0 + bk < K) {
      const float* bp = Bm + (size_t)(k0 + bk) * ldb + bn;
      if (bn + 3 < Nc) bv = *(const f4*)bp;
      else {
        #pragma unroll
        for (int j = 0; j < 4; j++) if (bn + j < Nc) bv[j] = bp[j];
      }
    }
    __syncthreads();   // previous iter's reads done before overwrite
    {
      int r = tid >> 2;
      As[kq * 4 + 0][r] = av[0];
      As[kq * 4 + 1][r] = av[1];
      As[kq * 4 + 2][r] = av[2];
      As[kq * 4 + 3][r] = av[3];
      *(f4*)&Bs[bk][(tid & 15) * 4] = bv;
    }
    __syncthreads();
    #pragma unroll
    for (int kk = 0; kk < 16; kk++) {
      f4 a = *(f4*)&As[kk][ty * 4];
      f4 b = *(f4*)&Bs[kk][tx * 4];
      #pragma unroll
      for (int i = 0; i < 4; i++)
        #pragma unroll
        for (int j = 0; j < 4; j++)
          acc[i][j] = fmaf(a[i], b[j], acc[i][j]);
    }
  }

  #pragma unroll
  for (int i = 0; i < 4; i++) {
    int m = m0 + ty * 4 + i;
    if (m >= Me) continue;
    size_t crow = (size_t)(GATH ? idxp[m] : m) * ldc;
    #pragma unroll
    for (int j = 0; j < 4; j++) {
      int n = n0 + tx * 4 + j;
      if (n >= Nc) continue;
      float vv = acc[i][j];
      float* p = Cmat + crow + n;
      if (EPI == 0) *p = vv;
      else if (EPI == 1) *p += vv;
      else if (EPI == 2) *p = vv / (1.f + expf(-vv));   // silu
      else if (EPI == 3) *p *= vv;
    }
  }
}

// ---------------- RoPE in place on [N, nh*64] ----------------
__global__ void rope_k(float* __restrict__ buf, int nh)
{
  int gid = blockIdx.x * 256 + threadIdx.x;
  int i = gid & 31;
  int rest = gid >> 5;
  int h = rest % nh;
  int n = rest / nh;
  int t = n & (cT - 1);
  // freq = 10000^(-i/32)
  float fr = __expf(-(float)i * (9.210340371976184f / 32.f));
  float ang = (float)t * fr;
  float sn, cs;
  sincosf(ang, &sn, &cs);
  float* p = buf + (size_t)n * (nh * cHD) + h * cHD + 2 * i;
  float r0 = p[0], r1 = p[1];
  p[0] = r0 * cs - r1 * sn;
  p[1] = r0 * sn + r1 * cs;
}

// ---------------- causal GQA attention, flash-style ----------------
// block = (64-query tile, head, batch); 4 waves, each wave owns 16 queries.
__global__ __launch_bounds__(256) void attn_k(const float* __restrict__ qb,
                                              const float* __restrict__ kb,
                                              const float* __restrict__ vb,
                                              float* __restrict__ yb)
{
  int qt = blockIdx.x * 64;
  int h  = blockIdx.y;
  int b  = blockIdx.z;
  int kvh = h >> 1;                    // n_rep = 2
  int tid = threadIdx.x, wv = tid >> 6, lane = tid & 63;

  __shared__ float qs[64][68];         // f4 reads, 2-way max
  __shared__ float Ks[64][68];
  __shared__ float Vs[64][65];         // scalar column reads, conflict-free
  __shared__ float pl[4][64];

  for (int idx = tid; idx < 1024; idx += 256) {
    int r = idx >> 4, c4 = (idx & 15) * 4;
    f4 v = *(const f4*)(qb + (size_t)(b * cT + qt + r) * cC + h * cHD + c4);
    qs[r][c4 + 0] = v[0] * 0.125f;     // fold in 1/sqrt(64)
    qs[r][c4 + 1] = v[1] * 0.125f;
    qs[r][c4 + 2] = v[2] * 0.125f;
    qs[r][c4 + 3] = v[3] * 0.125f;
  }

  float m[16], ssum[16], acc[16];
  #pragma unroll
  for (int r = 0; r < 16; r++) { m[r] = -INFINITY; ssum[r] = 0.f; acc[r] = 0.f; }

  for (int kt = 0; kt <= qt + 63; kt += 64) {
    __syncthreads();
    for (int idx = tid; idx < 1024; idx += 256) {
      int r = idx >> 4, c4 = (idx & 15) * 4;
      const float* kp = kb + (size_t)(b * cT + kt + r) * (cNKV * cHD) + kvh * cHD + c4;
      const float* vp = vb + (size_t)(b * cT + kt + r) * (cNKV * cHD) + kvh * cHD + c4;
      f4 kv = *(const f4*)kp;
      f4 vv = *(const f4*)vp;
      Ks[r][c4 + 0] = kv[0]; Ks[r][c4 + 1] = kv[1]; Ks[r][c4 + 2] = kv[2]; Ks[r][c4 + 3] = kv[3];
      Vs[r][c4 + 0] = vv[0]; Vs[r][c4 + 1] = vv[1]; Vs[r][c4 + 2] = vv[2]; Vs[r][c4 + 3] = vv[3];
    }
    __syncthreads();
    int key = kt + lane;
    #pragma unroll
    for (int r = 0; r < 16; r++) {
      int qi = qt + wv * 16 + r;
      if (kt > qi) continue;           // wave-uniform skip
      bool ok = key <= qi;
      float sc = 0.f;
      #pragma unroll
      for (int d4 = 0; d4 < 16; d4++) {
        f4 a  = *(const f4*)&qs[wv * 16 + r][d4 * 4];
        f4 kk = *(const f4*)&Ks[lane][d4 * 4];
        sc = fmaf(a[0], kk[0], sc);
        sc = fmaf(a[1], kk[1], sc);
        sc = fmaf(a[2], kk[2], sc);
        sc = fmaf(a[3], kk[3], sc);
      }
      if (!ok) sc = -INFINITY;
      float mt = sc;
      #pragma unroll
      for (int off = 32; off; off >>= 1) mt = fmaxf(mt, __shfl_xor(mt, off));
      float mn = fmaxf(m[r], mt);
      float p = ok ? __expf(sc - mn) : 0.f;
      float rs = __expf(m[r] - mn);    // 0 on first tile (m = -inf)
      m[r] = mn;
      float ps = p;
      #pragma unroll
      for (int off = 32; off; off >>= 1) ps += __shfl_xor(ps, off);
      ssum[r] = ssum[r] * rs + ps;
      pl[wv][lane] = p;
      float a = 0.f;
      #pragma unroll
      for (int j = 0; j < 64; j++) a = fmaf(pl[wv][j], Vs[j][lane], a);
      acc[r] = acc[r] * rs + a;
    }
  }
  #pragma unroll
  for (int r = 0; r < 16; r++) {
    int qi = qt + wv * 16 + r;
    yb[(size_t)(b * cT + qi) * cC + h * cHD + lane] = acc[r] / ssum[r];
  }
}

// ---------------- gate: logits, top-2, softmax, atomic routing ----------------
__global__ __launch_bounds__(256) void gate_k(const float* __restrict__ h2,
                                              const float* __restrict__ gw,
                                              int* __restrict__ sel, float* __restrict__ selw,
                                              int* __restrict__ cnt, int* __restrict__ elist)
{
  int wv = threadIdx.x >> 6, lane = threadIdx.x & 63;
  int n = blockIdx.x * 4 + wv;
  float acc[8] = {0.f, 0.f, 0.f, 0.f, 0.f, 0.f, 0.f, 0.f};
  for (int c = lane; c < cC; c += 64) {
    float hv = h2[(size_t)n * cC + c];
    f4 g0 = *(const f4*)(gw + c * 8);
    f4 g1 = *(const f4*)(gw + c * 8 + 4);
    acc[0] = fmaf(hv, g0[0], acc[0]); acc[1] = fmaf(hv, g0[1], acc[1]);
    acc[2] = fmaf(hv, g0[2], acc[2]); acc[3] = fmaf(hv, g0[3], acc[3]);
    acc[4] = fmaf(hv, g1[0], acc[4]); acc[5] = fmaf(hv, g1[1], acc[5]);
    acc[6] = fmaf(hv, g1[2], acc[6]); acc[7] = fmaf(hv, g1[3], acc[7]);
  }
  #pragma unroll
  for (int e = 0; e < 8; e++)
    #pragma unroll
    for (int off = 32; off; off >>= 1) acc[e] += __shfl_xor(acc[e], off);
  if (lane == 0) {
    int i0 = 0; float m0 = acc[0];
    #pragma unroll
    for (int e = 1; e < 8; e++) if (acc[e] > m0) { m0 = acc[e]; i0 = e; }
    int i1 = -1; float m1 = -INFINITY;
    #pragma unroll
    for (int e = 0; e < 8; e++) if (e != i0 && acc[e] > m1) { m1 = acc[e]; i1 = e; }
    float e1 = expf(m1 - m0);
    float p0 = 1.f / (1.f + e1);
    float p1 = e1 / (1.f + e1);
    sel[n * 2] = i0;  selw[n * 2] = p0;
    sel[n * 2 + 1] = i1; selw[n * 2 + 1] = p1;
    int pos0 = atomicAdd(&cnt[i0], 1); elist[(size_t)i0 * cN + pos0] = n * 2;
    int pos1 = atomicAdd(&cnt[i1], 1); elist[(size_t)i1 * cN + pos1] = n * 2 + 1;
  }
}

// ---------------- weighted combine of the two expert outputs ----------------
__global__ void combine_k(float* __restrict__ x, const float* __restrict__ eo,
                          const float* __restrict__ selw)
{
  int n = blockIdx.x, tid = threadIdx.x;
  float w0 = selw[n * 2], w1 = selw[n * 2 + 1];
  f4 a = *(const f4*)(eo + (size_t)(n * 2) * cC + tid * 4);
  f4 b = *(const f4*)(eo + (size_t)(n * 2 + 1) * cC + tid * 4);
  f4 xv = *(f4*)(x + (size_t)n * cC + tid * 4);
  xv += a * w0 + b * w1;
  *(f4*)(x + (size_t)n * cC + tid * 4) = xv;
}

// ---------------- logits: out[b,v] = hf[row_b] . wte[v] ----------------
__global__ __launch_bounds__(256) void logits_k(const float* __restrict__ hf,
                                                const float* __restrict__ wte,
                                                float* __restrict__ out)
{
  int wv = threadIdx.x >> 6, lane = threadIdx.x & 63;
  int v = blockIdx.x * 4 + wv;
  const float* wrow = wte + (size_t)v * cC;
  const float* r0 = hf + (size_t)(cT - 1) * cC;
  const float* r1 = hf + (size_t)(2 * cT - 1) * cC;
  float a0 = 0.f, a1 = 0.f;
  for (int c = lane * 4; c < cC; c += 256) {
    f4 w4 = *(const f4*)(wrow + c);
    f4 x0 = *(const f4*)(r0 + c);
    f4 x1 = *(const f4*)(r1 + c);
    a0 += dot4(w4, x0);
    a1 += dot4(w4, x1);
  }
  #pragma unroll
  for (int off = 32; off; off >>= 1) { a0 += __shfl_xor(a0, off); a1 += __shfl_xor(a1, off); }
  if (lane == 0) { out[v] = a0; out[cV + v] = a1; }
}

// =======================================================================
extern "C" void kernel_launch(void* const* d_in, const int* in_sizes, int n_in,
                              void* d_out, int out_size, void* d_ws, size_t ws_size,
                              hipStream_t stream)
{
  (void)in_sizes; (void)n_in; (void)out_size;
  const int*   idx  = (const int*)  d_in[0];
  const float* wte  = (const float*)d_in[1];
  const float* ln1w = (const float*)d_in[2];
  const float* p_wq = (const float*)d_in[3];
  const float* p_wk = (const float*)d_in[4];
  const float* p_wv = (const float*)d_in[5];
  const float* p_wo = (const float*)d_in[6];
  const float* ln2w = (const float*)d_in[7];
  const float* gw   = (const float*)d_in[8];
  const float* w1   = (const float*)d_in[9];
  const float* w2   = (const float*)d_in[10];
  const float* w3   = (const float*)d_in[11];
  const float* lnfw = (const float*)d_in[12];
  float* out = (float*)d_out;

  float* ws = (float*)d_ws;
  size_t o = 0;
  float* x    = ws + o; o += (size_t)cN * cC;
  float* h    = ws + o; o += (size_t)cN * cC;
  float* q    = ws + o; o += (size_t)cN * cC;
  float* kbuf = ws + o; o += (size_t)cN * cNKV * cHD;
  float* vbuf = ws + o; o += (size_t)cN * cNKV * cHD;
  float* y    = ws + o; o += (size_t)cN * cC;
  float* acts = ws + o; o += (size_t)cN * 2 * cHID;
  float* eo   = ws + o; o += (size_t)cN * 2 * cC;
  float* selw = ws + o; o += (size_t)cN * 2;
  int* sel    = (int*)(ws + o); o += (size_t)cN * 2;
  int* cnt    = (int*)(ws + o); o += 8;
  int* elist  = (int*)(ws + o); o += (size_t)cE * cN;
  if (ws_size < o * sizeof(float)) return;   // ~103.5 MB needed

  embed_k<<<cN, 256, 0, stream>>>(idx, wte, x);

  for (int l = 0; l < 2; l++) {
    // ---- attention ----
    rmsnorm_k<<<cN, 256, 0, stream>>>(x, ln1w + (size_t)l * cC, h);
    gemm64<0,0><<<dim3(16, 32), 256, 0, stream>>>(h, p_wq + (size_t)l * cC * 1024, q,
        cN, 1024, cC, cC, 1024, 1024, nullptr, nullptr);
    gemm64<0,0><<<dim3(8, 32), 256, 0, stream>>>(h, p_wk + (size_t)l * cC * 512, kbuf,
        cN, 512, cC, cC, 512, 512, nullptr, nullptr);
    gemm64<0,0><<<dim3(8, 32), 256, 0, stream>>>(h, p_wv + (size_t)l * cC * 512, vbuf,
        cN, 512, cC, cC, 512, 512, nullptr, nullptr);
    rope_k<<<(cN * cNH * 32) / 256, 256, 0, stream>>>(q, cNH);
    rope_k<<<(cN * cNKV * 32) / 256, 256, 0, stream>>>(kbuf, cNKV);
    attn_k<<<dim3(cT / 64, cNH, cB), 256, 0, stream>>>(q, kbuf, vbuf, y);
    gemm64<1,0><<<dim3(16, 32), 256, 0, stream>>>(y, p_wo + (size_t)l * 1024 * cC, x,
        cN, cC, 1024, 1024, cC, cC, nullptr, nullptr);   // x += y @ wo

    // ---- MoE ----
    rmsnorm_k<<<cN, 256, 0, stream>>>(x, ln2w + (size_t)l * cC, h);
    hipMemsetAsync(cnt, 0, cE * sizeof(int), stream);
    gate_k<<<cN / 4, 256, 0, stream>>>(h, gw + (size_t)l * cC * cE, sel, selw, cnt, elist);
    // acts[slot] = silu(h[token] @ w1[e])
    gemm64<2,1><<<dim3(43, 32, 8), 256, 0, stream>>>(h, w1 + (size_t)l * cE * cC * cHID, acts,
        0, cHID, cC, cC, cHID, cHID, elist, cnt);
    // acts[slot] *= h[token] @ w3[e]
    gemm64<3,1><<<dim3(43, 32, 8), 256, 0, stream>>>(h, w3 + (size_t)l * cE * cC * cHID, acts,
        0, cHID, cC, cC, cHID, cHID, elist, cnt);
    // eo[slot] = acts[slot] @ w2[e]
    gemm64<0,2><<<dim3(16, 32, 8), 256, 0, stream>>>(acts, w2 + (size_t)l * cE * cHID * cC, eo,
        0, cC, cHID, cHID, cC, cC, elist, cnt);
    combine_k<<<cN, 256, 0, stream>>>(x, eo, selw);
  }

  rmsnorm_k<<<cN, 256, 0, stream>>>(x, lnfw, h);
  logits_k<<<cV / 4, 256, 0, stream>>>(h, wte, out);
}

// Round 2
// 2658.259 us; speedup vs baseline: 1.5737x; 1.5737x over previous
//
#include <hip/hip_runtime.h>
#include <hip/hip_bf16.h>
#include <math.h>

using f4 = __attribute__((ext_vector_type(4))) float;
using sh4 = __attribute__((ext_vector_type(4))) short;
using sh8 = __attribute__((ext_vector_type(8))) short;

constexpr int cV = 32000, cC = 1024;
constexpr int cNH = 16, cNKV = 8, cHD = 64;
constexpr int cE = 8, cHID = 2728;
constexpr int cB = 2, cT = 1024, cN = cB * cT;

__device__ inline float dot4(f4 a, f4 b) { return a[0]*b[0] + a[1]*b[1] + a[2]*b[2] + a[3]*b[3]; }

__device__ inline short f2bf(float f) {
  unsigned u = __builtin_bit_cast(unsigned, f);
  u += 0x7fff + ((u >> 16) & 1);          // RNE
  return (short)(u >> 16);
}

// ---------------- embedding gather ----------------
__global__ void embed_k(const int* __restrict__ idx, const float* __restrict__ wte,
                        float* __restrict__ x)
{
  int n = blockIdx.x, tid = threadIdx.x;
  size_t row = (size_t)idx[n] * cC;
  *(f4*)(x + (size_t)n * cC + tid * 4) = *(const f4*)(wte + row + tid * 4);
}

// ---------------- rmsnorm ----------------
__global__ __launch_bounds__(256) void rmsnorm_k(const float* __restrict__ in,
                                                 const float* __restrict__ w,
                                                 float* __restrict__ out)
{
  int n = blockIdx.x, tid = threadIdx.x;
  f4 v = *(const f4*)(in + (size_t)n * cC + tid * 4);
  float s = dot4(v, v);
  #pragma unroll
  for (int off = 32; off; off >>= 1) s += __shfl_xor(s, off);
  __shared__ float red[4];
  if ((tid & 63) == 0) red[tid >> 6] = s;
  __syncthreads();
  float tot = red[0] + red[1] + red[2] + red[3];
  float inv = rsqrtf(tot * (1.0f / cC) + 1e-5f);
  f4 wv = *(const f4*)(w + tid * 4);
  f4 o = v * inv * wv;
  *(f4*)(out + (size_t)n * cC + tid * 4) = o;
}

// ============ bf16 MFMA GEMM: 128x128 tile, BK=32, 4 waves (2x2) ============
// fp32 in HBM, converted to bf16 during LDS staging; fp32 accum/out.
// EPI: 0 store, 1 +=, 2 silu-store, 3 *= (in-place)
// GATH: 0 none; 1 A-row = list[m]>>1, C-row = list[m]; 2 A-row = C-row = list[m]
template<int EPI, int GATH>
__global__ __launch_bounds__(256, 2) void mgemm(
    const float* __restrict__ A, const float* __restrict__ Bm, float* __restrict__ Cmat,
    int M, int Nc, int K, int lda, int ldb, int ldc,
    const int* __restrict__ gidx, const int* __restrict__ gcnt)
{
  int Me = M;
  const int* idxp = nullptr;
  if (GATH) {
    int e = blockIdx.z;
    Me = gcnt[e];
    idxp = gidx + (size_t)e * cN;
    Bm += (size_t)e * (size_t)K * ldb;     // per-expert weight slab
  }
  int m0 = blockIdx.y * 128;
  if (m0 >= Me) return;
  int n0 = blockIdx.x * 128;

  // 40-short (80B) stride: 16B slot index walks (row*5)&7 -> all 8 bank groups
  __shared__ short As[128][40];            // [m][k] bf16
  __shared__ short Bs[128][40];            // [n][k] bf16 (transposed at staging)

  int tid = threadIdx.x;
  int lane = tid & 63, wv = tid >> 6;
  int wr = wv >> 1, wc = wv & 1;

  // ---- staging maps ----
  int ar = tid >> 1;                       // A tile row 0..127
  int ah = (tid & 1) * 16;                 // A col half (fp32 cols)
  bool arv = (m0 + ar) < Me;
  size_t asrc = 0;
  if (arv) {
    int t = GATH ? idxp[m0 + ar] : (m0 + ar);
    asrc = (size_t)((GATH == 1) ? (t >> 1) : t) * lda;
  }
  int bn = (tid >> 3) * 4;                 // B tile col (n) 0..124
  int bk = (tid & 7) * 4;                  // B k-sub 0..28
  bool bcv = (n0 + bn) < Nc;               // Nc % 4 == 0 always

  f4 av[4], bv[4];
  auto loadT = [&](int k0) {
    #pragma unroll
    for (int q = 0; q < 4; q++) {
      int col = k0 + ah + q * 4;
      av[q] = (arv && col < K) ? *(const f4*)(A + asrc + col) : f4{0.f, 0.f, 0.f, 0.f};
    }
    #pragma unroll
    for (int r = 0; r < 4; r++) {
      int kg = k0 + bk + r;
      bv[r] = (bcv && kg < K) ? *(const f4*)(Bm + (size_t)kg * ldb + n0 + bn)
                              : f4{0.f, 0.f, 0.f, 0.f};
    }
  };
  auto storeT = [&]() {
    sh8 lo, hi;
    #pragma unroll
    for (int j = 0; j < 4; j++) {
      lo[j]     = f2bf(av[0][j]);
      lo[4 + j] = f2bf(av[1][j]);
      hi[j]     = f2bf(av[2][j]);
      hi[4 + j] = f2bf(av[3][j]);
    }
    *(sh8*)&As[ar][ah] = lo;
    *(sh8*)&As[ar][ah + 8] = hi;
    #pragma unroll
    for (int j = 0; j < 4; j++) {
      sh4 col = { f2bf(bv[0][j]), f2bf(bv[1][j]), f2bf(bv[2][j]), f2bf(bv[3][j]) };
      *(sh4*)&Bs[bn + j][bk] = col;
    }
  };

  f4 acc[4][4] = {};
  int fr = lane & 15;                      // fragment row/col within 16
  int kb = (lane >> 4) * 8;                // fragment k base

  loadT(0);
  for (int k0 = 0; k0 < K; k0 += 32) {
    __syncthreads();
    storeT();
    __syncthreads();
    if (k0 + 32 < K) loadT(k0 + 32);       // prefetch next tile into regs
    sh8 af[4], bf[4];
    #pragma unroll
    for (int m = 0; m < 4; m++) af[m] = *(sh8*)&As[wr * 64 + m * 16 + fr][kb];
    #pragma unroll
    for (int n = 0; n < 4; n++) bf[n] = *(sh8*)&Bs[wc * 64 + n * 16 + fr][kb];
    #pragma unroll
    for (int m = 0; m < 4; m++)
      #pragma unroll
      for (int n = 0; n < 4; n++)
        acc[m][n] = __builtin_amdgcn_mfma_f32_16x16x32_bf16(af[m], bf[n], acc[m][n], 0, 0, 0);
  }

  // ---- epilogue: C row = (lane>>4)*4 + i, col = lane&15 ----
  int rq = (lane >> 4) * 4;
  #pragma unroll
  for (int m = 0; m < 4; m++) {
    #pragma unroll
    for (int i = 0; i < 4; i++) {
      int mrow = m0 + wr * 64 + m * 16 + rq + i;
      if (mrow >= Me) continue;
      size_t crow = (size_t)(GATH ? idxp[mrow] : mrow) * ldc;
      #pragma unroll
      for (int n = 0; n < 4; n++) {
        int ncol = n0 + wc * 64 + n * 16 + fr;
        if (ncol >= Nc) continue;
        float vv = acc[m][n][i];
        float* p = Cmat + crow + ncol;
        if (EPI == 0) *p = vv;
        else if (EPI == 1) *p += vv;
        else if (EPI == 2) *p = vv / (1.f + expf(-vv));   // silu
        else if (EPI == 3) *p *= vv;
      }
    }
  }
}

// ---------------- RoPE in place on [N, nh*64] ----------------
__global__ void rope_k(float* __restrict__ buf, int nh)
{
  int gid = blockIdx.x * 256 + threadIdx.x;
  int i = gid & 31;
  int rest = gid >> 5;
  int h = rest % nh;
  int n = rest / nh;
  int t = n & (cT - 1);
  float fr = __expf(-(float)i * (9.210340371976184f / 32.f));
  float ang = (float)t * fr;
  float sn, cs;
  sincosf(ang, &sn, &cs);
  float* p = buf + (size_t)n * (nh * cHD) + h * cHD + 2 * i;
  float r0 = p[0], r1 = p[1];
  p[0] = r0 * cs - r1 * sn;
  p[1] = r0 * sn + r1 * cs;
}

// ---------------- causal GQA attention, flash-style ----------------
__global__ __launch_bounds__(256) void attn_k(const float* __restrict__ qb,
                                              const float* __restrict__ kb,
                                              const float* __restrict__ vb,
                                              float* __restrict__ yb)
{
  int qt = blockIdx.x * 64;
  int h  = blockIdx.y;
  int b  = blockIdx.z;
  int kvh = h >> 1;                    // n_rep = 2
  int tid = threadIdx.x, wv = tid >> 6, lane = tid & 63;

  __shared__ float qs[64][68];
  __shared__ float Ks[64][68];
  __shared__ float Vs[64][65];
  __shared__ float pl[4][64];

  for (int idx = tid; idx < 1024; idx += 256) {
    int r = idx >> 4, c4 = (idx & 15) * 4;
    f4 v = *(const f4*)(qb + (size_t)(b * cT + qt + r) * cC + h * cHD + c4);
    qs[r][c4 + 0] = v[0] * 0.125f;
    qs[r][c4 + 1] = v[1] * 0.125f;
    qs[r][c4 + 2] = v[2] * 0.125f;
    qs[r][c4 + 3] = v[3] * 0.125f;
  }

  float m[16], ssum[16], acc[16];
  #pragma unroll
  for (int r = 0; r < 16; r++) { m[r] = -INFINITY; ssum[r] = 0.f; acc[r] = 0.f; }

  for (int kt = 0; kt <= qt + 63; kt += 64) {
    __syncthreads();
    for (int idx = tid; idx < 1024; idx += 256) {
      int r = idx >> 4, c4 = (idx & 15) * 4;
      const float* kp = kb + (size_t)(b * cT + kt + r) * (cNKV * cHD) + kvh * cHD + c4;
      const float* vp = vb + (size_t)(b * cT + kt + r) * (cNKV * cHD) + kvh * cHD + c4;
      f4 kv = *(const f4*)kp;
      f4 vv = *(const f4*)vp;
      Ks[r][c4 + 0] = kv[0]; Ks[r][c4 + 1] = kv[1]; Ks[r][c4 + 2] = kv[2]; Ks[r][c4 + 3] = kv[3];
      Vs[r][c4 + 0] = vv[0]; Vs[r][c4 + 1] = vv[1]; Vs[r][c4 + 2] = vv[2]; Vs[r][c4 + 3] = vv[3];
    }
    __syncthreads();
    int key = kt + lane;
    #pragma unroll
    for (int r = 0; r < 16; r++) {
      int qi = qt + wv * 16 + r;
      if (kt > qi) continue;
      bool ok = key <= qi;
      float sc = 0.f;
      #pragma unroll
      for (int d4 = 0; d4 < 16; d4++) {
        f4 a  = *(const f4*)&qs[wv * 16 + r][d4 * 4];
        f4 kk = *(const f4*)&Ks[lane][d4 * 4];
        sc = fmaf(a[0], kk[0], sc);
        sc = fmaf(a[1], kk[1], sc);
        sc = fmaf(a[2], kk[2], sc);
        sc = fmaf(a[3], kk[3], sc);
      }
      if (!ok) sc = -INFINITY;
      float mt = sc;
      #pragma unroll
      for (int off = 32; off; off >>= 1) mt = fmaxf(mt, __shfl_xor(mt, off));
      float mn = fmaxf(m[r], mt);
      float p = ok ? __expf(sc - mn) : 0.f;
      float rs = __expf(m[r] - mn);
      m[r] = mn;
      float ps = p;
      #pragma unroll
      for (int off = 32; off; off >>= 1) ps += __shfl_xor(ps, off);
      ssum[r] = ssum[r] * rs + ps;
      pl[wv][lane] = p;
      float a = 0.f;
      #pragma unroll
      for (int j = 0; j < 64; j++) a = fmaf(pl[wv][j], Vs[j][lane], a);
      acc[r] = acc[r] * rs + a;
    }
  }
  #pragma unroll
  for (int r = 0; r < 16; r++) {
    int qi = qt + wv * 16 + r;
    yb[(size_t)(b * cT + qi) * cC + h * cHD + lane] = acc[r] / ssum[r];
  }
}

// ---------------- gate: logits, top-2, softmax, atomic routing ----------------
__global__ __launch_bounds__(256) void gate_k(const float* __restrict__ h2,
                                              const float* __restrict__ gw,
                                              int* __restrict__ sel, float* __restrict__ selw,
                                              int* __restrict__ cnt, int* __restrict__ elist)
{
  int wv = threadIdx.x >> 6, lane = threadIdx.x & 63;
  int n = blockIdx.x * 4 + wv;
  float acc[8] = {0.f, 0.f, 0.f, 0.f, 0.f, 0.f, 0.f, 0.f};
  for (int c = lane; c < cC; c += 64) {
    float hv = h2[(size_t)n * cC + c];
    f4 g0 = *(const f4*)(gw + c * 8);
    f4 g1 = *(const f4*)(gw + c * 8 + 4);
    acc[0] = fmaf(hv, g0[0], acc[0]); acc[1] = fmaf(hv, g0[1], acc[1]);
    acc[2] = fmaf(hv, g0[2], acc[2]); acc[3] = fmaf(hv, g0[3], acc[3]);
    acc[4] = fmaf(hv, g1[0], acc[4]); acc[5] = fmaf(hv, g1[1], acc[5]);
    acc[6] = fmaf(hv, g1[2], acc[6]); acc[7] = fmaf(hv, g1[3], acc[7]);
  }
  #pragma unroll
  for (int e = 0; e < 8; e++)
    #pragma unroll
    for (int off = 32; off; off >>= 1) acc[e] += __shfl_xor(acc[e], off);
  if (lane == 0) {
    int i0 = 0; float m0 = acc[0];
    #pragma unroll
    for (int e = 1; e < 8; e++) if (acc[e] > m0) { m0 = acc[e]; i0 = e; }
    int i1 = -1; float m1 = -INFINITY;
    #pragma unroll
    for (int e = 0; e < 8; e++) if (e != i0 && acc[e] > m1) { m1 = acc[e]; i1 = e; }
    float e1 = expf(m1 - m0);
    float p0 = 1.f / (1.f + e1);
    float p1 = e1 / (1.f + e1);
    sel[n * 2] = i0;  selw[n * 2] = p0;
    sel[n * 2 + 1] = i1; selw[n * 2 + 1] = p1;
    int pos0 = atomicAdd(&cnt[i0], 1); elist[(size_t)i0 * cN + pos0] = n * 2;
    int pos1 = atomicAdd(&cnt[i1], 1); elist[(size_t)i1 * cN + pos1] = n * 2 + 1;
  }
}

// ---------------- weighted combine ----------------
__global__ void combine_k(float* __restrict__ x, const float* __restrict__ eo,
                          const float* __restrict__ selw)
{
  int n = blockIdx.x, tid = threadIdx.x;
  float w0 = selw[n * 2], w1 = selw[n * 2 + 1];
  f4 a = *(const f4*)(eo + (size_t)(n * 2) * cC + tid * 4);
  f4 b = *(const f4*)(eo + (size_t)(n * 2 + 1) * cC + tid * 4);
  f4 xv = *(f4*)(x + (size_t)n * cC + tid * 4);
  xv += a * w0 + b * w1;
  *(f4*)(x + (size_t)n * cC + tid * 4) = xv;
}

// ---------------- logits ----------------
__global__ __launch_bounds__(256) void logits_k(const float* __restrict__ hf,
                                                const float* __restrict__ wte,
                                                float* __restrict__ out)
{
  int wv = threadIdx.x >> 6, lane = threadIdx.x & 63;
  int v = blockIdx.x * 4 + wv;
  const float* wrow = wte + (size_t)v * cC;
  const float* r0 = hf + (size_t)(cT - 1) * cC;
  const float* r1 = hf + (size_t)(2 * cT - 1) * cC;
  float a0 = 0.f, a1 = 0.f;
  for (int c = lane * 4; c < cC; c += 256) {
    f4 w4 = *(const f4*)(wrow + c);
    f4 x0 = *(const f4*)(r0 + c);
    f4 x1 = *(const f4*)(r1 + c);
    a0 += dot4(w4, x0);
    a1 += dot4(w4, x1);
  }
  #pragma unroll
  for (int off = 32; off; off >>= 1) { a0 += __shfl_xor(a0, off); a1 += __shfl_xor(a1, off); }
  if (lane == 0) { out[v] = a0; out[cV + v] = a1; }
}

// =======================================================================
extern "C" void kernel_launch(void* const* d_in, const int* in_sizes, int n_in,
                              void* d_out, int out_size, void* d_ws, size_t ws_size,
                              hipStream_t stream)
{
  (void)in_sizes; (void)n_in; (void)out_size;
  const int*   idx  = (const int*)  d_in[0];
  const float* wte  = (const float*)d_in[1];
  const float* ln1w = (const float*)d_in[2];
  const float* p_wq = (const float*)d_in[3];
  const float* p_wk = (const float*)d_in[4];
  const float* p_wv = (const float*)d_in[5];
  const float* p_wo = (const float*)d_in[6];
  const float* ln2w = (const float*)d_in[7];
  const float* gw   = (const float*)d_in[8];
  const float* w1   = (const float*)d_in[9];
  const float* w2   = (const float*)d_in[10];
  const float* w3   = (const float*)d_in[11];
  const float* lnfw = (const float*)d_in[12];
  float* out = (float*)d_out;

  float* ws = (float*)d_ws;
  size_t o = 0;
  float* x    = ws + o; o += (size_t)cN * cC;
  float* h    = ws + o; o += (size_t)cN * cC;
  float* q    = ws + o; o += (size_t)cN * cC;
  float* kbuf = ws + o; o += (size_t)cN * cNKV * cHD;
  float* vbuf = ws + o; o += (size_t)cN * cNKV * cHD;
  float* y    = ws + o; o += (size_t)cN * cC;
  float* acts = ws + o; o += (size_t)cN * 2 * cHID;
  float* eo   = ws + o; o += (size_t)cN * 2 * cC;
  float* selw = ws + o; o += (size_t)cN * 2;
  int* sel    = (int*)(ws + o); o += (size_t)cN * 2;
  int* cnt    = (int*)(ws + o); o += 8;
  int* elist  = (int*)(ws + o); o += (size_t)cE * cN;
  if (ws_size < o * sizeof(float)) return;

  embed_k<<<cN, 256, 0, stream>>>(idx, wte, x);

  for (int l = 0; l < 2; l++) {
    // ---- attention ----
    rmsnorm_k<<<cN, 256, 0, stream>>>(x, ln1w + (size_t)l * cC, h);
    mgemm<0,0><<<dim3(8, 16), 256, 0, stream>>>(h, p_wq + (size_t)l * cC * 1024, q,
        cN, 1024, cC, cC, 1024, 1024, nullptr, nullptr);
    mgemm<0,0><<<dim3(4, 16), 256, 0, stream>>>(h, p_wk + (size_t)l * cC * 512, kbuf,
        cN, 512, cC, cC, 512, 512, nullptr, nullptr);
    mgemm<0,0><<<dim3(4, 16), 256, 0, stream>>>(h, p_wv + (size_t)l * cC * 512, vbuf,
        cN, 512, cC, cC, 512, 512, nullptr, nullptr);
    rope_k<<<(cN * cNH * 32) / 256, 256, 0, stream>>>(q, cNH);
    rope_k<<<(cN * cNKV * 32) / 256, 256, 0, stream>>>(kbuf, cNKV);
    attn_k<<<dim3(cT / 64, cNH, cB), 256, 0, stream>>>(q, kbuf, vbuf, y);
    mgemm<1,0><<<dim3(8, 16), 256, 0, stream>>>(y, p_wo + (size_t)l * 1024 * cC, x,
        cN, cC, 1024, 1024, cC, cC, nullptr, nullptr);   // x += y @ wo

    // ---- MoE ----
    rmsnorm_k<<<cN, 256, 0, stream>>>(x, ln2w + (size_t)l * cC, h);
    hipMemsetAsync(cnt, 0, cE * sizeof(int), stream);
    gate_k<<<cN / 4, 256, 0, stream>>>(h, gw + (size_t)l * cC * cE, sel, selw, cnt, elist);
    // acts[slot] = silu(h[token] @ w1[e])
    mgemm<2,1><<<dim3(22, 16, 8), 256, 0, stream>>>(h, w1 + (size_t)l * cE * cC * cHID, acts,
        0, cHID, cC, cC, cHID, cHID, elist, cnt);
    // acts[slot] *= h[token] @ w3[e]
    mgemm<3,1><<<dim3(22, 16, 8), 256, 0, stream>>>(h, w3 + (size_t)l * cE * cC * cHID, acts,
        0, cHID, cC, cC, cHID, cHID, elist, cnt);
    // eo[slot] = acts[slot] @ w2[e]
    mgemm<0,2><<<dim3(8, 16, 8), 256, 0, stream>>>(acts, w2 + (size_t)l * cE * cHID * cC, eo,
        0, cC, cHID, cHID, cC, cC, elist, cnt);
    combine_k<<<cN, 256, 0, stream>>>(x, eo, selw);
  }

  rmsnorm_k<<<cN, 256, 0, stream>>>(x, lnfw, h);
  logits_k<<<cV / 4, 256, 0, stream>>>(h, wte, out);
}

// Round 3
// 2022.733 us; speedup vs baseline: 2.0681x; 1.3142x over previous
//
#include <hip/hip_runtime.h>
#include <hip/hip_bf16.h>
#include <math.h>

using f4 = __attribute__((ext_vector_type(4))) float;
using f16x = __attribute__((ext_vector_type(16))) float;
using sh4 = __attribute__((ext_vector_type(4))) short;
using sh8 = __attribute__((ext_vector_type(8))) short;

constexpr int cV = 32000, cC = 1024;
constexpr int cNH = 16, cNKV = 8, cHD = 64;
constexpr int cE = 8, cHID = 2728;
constexpr int cB = 2, cT = 1024, cN = cB * cT;

__device__ inline float dot4(f4 a, f4 b) { return a[0]*b[0] + a[1]*b[1] + a[2]*b[2] + a[3]*b[3]; }

__device__ inline short f2bf(float f) {
  unsigned u = __builtin_bit_cast(unsigned, f);
  u += 0x7fff + ((u >> 16) & 1);          // RNE
  return (short)(u >> 16);
}

// ---------------- embedding gather ----------------
__global__ void embed_k(const int* __restrict__ idx, const float* __restrict__ wte,
                        float* __restrict__ x)
{
  int n = blockIdx.x, tid = threadIdx.x;
  size_t row = (size_t)idx[n] * cC;
  *(f4*)(x + (size_t)n * cC + tid * 4) = *(const f4*)(wte + row + tid * 4);
}

// ---------------- rmsnorm ----------------
__global__ __launch_bounds__(256) void rmsnorm_k(const float* __restrict__ in,
                                                 const float* __restrict__ w,
                                                 float* __restrict__ out)
{
  int n = blockIdx.x, tid = threadIdx.x;
  f4 v = *(const f4*)(in + (size_t)n * cC + tid * 4);
  float s = dot4(v, v);
  #pragma unroll
  for (int off = 32; off; off >>= 1) s += __shfl_xor(s, off);
  __shared__ float red[4];
  if ((tid & 63) == 0) red[tid >> 6] = s;
  __syncthreads();
  float tot = red[0] + red[1] + red[2] + red[3];
  float inv = rsqrtf(tot * (1.0f / cC) + 1e-5f);
  f4 wv = *(const f4*)(w + tid * 4);
  f4 o = v * inv * wv;
  *(f4*)(out + (size_t)n * cC + tid * 4) = o;
}

// ============ bf16 MFMA GEMM: 128x128 tile, BK=32, 4 waves (2x2) ============
// EPI: 0 store, 1 +=, 2 silu-store, 3 *= (in-place)
// GATH: 0 none; 1 A-row = list[m]>>1, C-row = list[m]; 2 A-row = C-row = list[m]
template<int EPI, int GATH>
__global__ __launch_bounds__(256, 2) void mgemm(
    const float* __restrict__ A, const float* __restrict__ Bm, float* __restrict__ Cmat,
    int M, int Nc, int K, int lda, int ldb, int ldc,
    const int* __restrict__ gidx, const int* __restrict__ gcnt)
{
  int Me = M;
  const int* idxp = nullptr;
  if (GATH) {
    int e = blockIdx.z;
    Me = gcnt[e];
    idxp = gidx + (size_t)e * cN;
    Bm += (size_t)e * (size_t)K * ldb;     // per-expert weight slab
  }
  int m0 = blockIdx.y * 128;
  if (m0 >= Me) return;
  int n0 = blockIdx.x * 128;

  __shared__ short As[128][40];            // [m][k] bf16
  __shared__ short Bs[128][40];            // [n][k] bf16 (transposed at staging)

  int tid = threadIdx.x;
  int lane = tid & 63, wv = tid >> 6;
  int wr = wv >> 1, wc = wv & 1;

  int ar = tid >> 1;
  int ah = (tid & 1) * 16;
  bool arv = (m0 + ar) < Me;
  size_t asrc = 0;
  if (arv) {
    int t = GATH ? idxp[m0 + ar] : (m0 + ar);
    asrc = (size_t)((GATH == 1) ? (t >> 1) : t) * lda;
  }
  int bn = (tid >> 3) * 4;
  int bk = (tid & 7) * 4;
  bool bcv = (n0 + bn) < Nc;

  f4 av[4], bv[4];
  auto loadT = [&](int k0) {
    #pragma unroll
    for (int q = 0; q < 4; q++) {
      int col = k0 + ah + q * 4;
      av[q] = (arv && col < K) ? *(const f4*)(A + asrc + col) : f4{0.f, 0.f, 0.f, 0.f};
    }
    #pragma unroll
    for (int r = 0; r < 4; r++) {
      int kg = k0 + bk + r;
      bv[r] = (bcv && kg < K) ? *(const f4*)(Bm + (size_t)kg * ldb + n0 + bn)
                              : f4{0.f, 0.f, 0.f, 0.f};
    }
  };
  auto storeT = [&]() {
    sh8 lo, hi;
    #pragma unroll
    for (int j = 0; j < 4; j++) {
      lo[j]     = f2bf(av[0][j]);
      lo[4 + j] = f2bf(av[1][j]);
      hi[j]     = f2bf(av[2][j]);
      hi[4 + j] = f2bf(av[3][j]);
    }
    *(sh8*)&As[ar][ah] = lo;
    *(sh8*)&As[ar][ah + 8] = hi;
    #pragma unroll
    for (int j = 0; j < 4; j++) {
      sh4 col = { f2bf(bv[0][j]), f2bf(bv[1][j]), f2bf(bv[2][j]), f2bf(bv[3][j]) };
      *(sh4*)&Bs[bn + j][bk] = col;
    }
  };

  f4 acc[4][4] = {};
  int fr = lane & 15;
  int kb = (lane >> 4) * 8;

  loadT(0);
  for (int k0 = 0; k0 < K; k0 += 32) {
    __syncthreads();
    storeT();
    __syncthreads();
    if (k0 + 32 < K) loadT(k0 + 32);
    sh8 af[4], bf[4];
    #pragma unroll
    for (int m = 0; m < 4; m++) af[m] = *(sh8*)&As[wr * 64 + m * 16 + fr][kb];
    #pragma unroll
    for (int n = 0; n < 4; n++) bf[n] = *(sh8*)&Bs[wc * 64 + n * 16 + fr][kb];
    #pragma unroll
    for (int m = 0; m < 4; m++)
      #pragma unroll
      for (int n = 0; n < 4; n++)
        acc[m][n] = __builtin_amdgcn_mfma_f32_16x16x32_bf16(af[m], bf[n], acc[m][n], 0, 0, 0);
  }

  int rq = (lane >> 4) * 4;
  #pragma unroll
  for (int m = 0; m < 4; m++) {
    #pragma unroll
    for (int i = 0; i < 4; i++) {
      int mrow = m0 + wr * 64 + m * 16 + rq + i;
      if (mrow >= Me) continue;
      size_t crow = (size_t)(GATH ? idxp[mrow] : mrow) * ldc;
      #pragma unroll
      for (int n = 0; n < 4; n++) {
        int ncol = n0 + wc * 64 + n * 16 + fr;
        if (ncol >= Nc) continue;
        float vv = acc[m][n][i];
        float* p = Cmat + crow + ncol;
        if (EPI == 0) *p = vv;
        else if (EPI == 1) *p += vv;
        else if (EPI == 2) *p = vv / (1.f + expf(-vv));   // silu
        else if (EPI == 3) *p *= vv;
      }
    }
  }
}

// ---------------- RoPE in place on [N, nh*64] ----------------
__global__ void rope_k(float* __restrict__ buf, int nh)
{
  int gid = blockIdx.x * 256 + threadIdx.x;
  int i = gid & 31;
  int rest = gid >> 5;
  int h = rest % nh;
  int n = rest / nh;
  int t = n & (cT - 1);
  float fr = __expf(-(float)i * (9.210340371976184f / 32.f));
  float ang = (float)t * fr;
  float sn, cs;
  sincosf(ang, &sn, &cs);
  float* p = buf + (size_t)n * (nh * cHD) + h * cHD + 2 * i;
  float r0 = p[0], r1 = p[1];
  p[0] = r0 * cs - r1 * sn;
  p[1] = r0 * sn + r1 * cs;
}

// ======== MFMA flash attention: block = 64 q-rows, 2 waves x 32 rows ========
// 32x32x16 bf16 MFMA for QK^T and PV. K_lds/Vt/P_lds XOR-swizzled (G4).
__global__ __launch_bounds__(128) void attn_k(const float* __restrict__ qb,
                                              const float* __restrict__ kb,
                                              const float* __restrict__ vb,
                                              float* __restrict__ yb)
{
  int h = blockIdx.y, b = blockIdx.z;
  // causal load-balance: batch 1 walks q-tiles in reverse so each CU's block
  // pair (lin, lin+256) covers tiles q and 15-q (uniform work).
  int qt = (b == 1) ? (15 - blockIdx.x) : blockIdx.x;
  int qb0 = qt * 64;
  int kvh = h >> 1;                        // n_rep = 2
  int tid = threadIdx.x, w = tid >> 6, l = tid & 63;
  int c = l & 31, g = l >> 5;

  __shared__ short Kl[64 * 64];            // [key][d], swizzled 16B slots
  __shared__ short Vt[64 * 64];            // [d][key], swizzled
  __shared__ short Pl[2][32 * 64];         // per-wave P, swizzled

  // ---- Q fragments (A-frag: row c, k-elems g*8..+8 per 16-chunk) ----
  sh8 aq[4];
  {
    int grow = qb0 + w * 32 + c;
    const float* qp = qb + (size_t)(b * cT + grow) * cC + h * cHD + g * 8;
    #pragma unroll
    for (int k = 0; k < 4; k++) {
      f4 x0 = *(const f4*)(qp + k * 16);
      f4 x1 = *(const f4*)(qp + k * 16 + 4);
      sh8 v;
      #pragma unroll
      for (int j = 0; j < 4; j++) { v[j] = f2bf(x0[j] * 0.125f); v[4 + j] = f2bf(x1[j] * 0.125f); }
      aq[k] = v;
    }
  }

  float m[16], ll[16];
  f16x o0 = {}, o1 = {};
  #pragma unroll
  for (int i = 0; i < 16; i++) { m[i] = -1e30f; ll[i] = 0.f; }

  for (int kt = 0; kt <= qb0; kt += 64) {
    __syncthreads();
    // ---- stage K [64][64] bf16, swizzled ----
    #pragma unroll
    for (int it = 0; it < 4; it++) {
      int s = tid + 128 * it;
      int row = s >> 3, o16 = s & 7;
      const float* kp = kb + (size_t)(b * cT + kt + row) * (cNKV * cHD) + kvh * cHD + o16 * 8;
      f4 x0 = *(const f4*)kp, x1 = *(const f4*)(kp + 4);
      sh8 v;
      #pragma unroll
      for (int j = 0; j < 4; j++) { v[j] = f2bf(x0[j]); v[4 + j] = f2bf(x1[j]); }
      *(sh8*)((char*)Kl + row * 128 + ((o16 ^ (row & 7)) * 16)) = v;
    }
    // ---- stage V transposed: Vt[d][key], b32 writes (2 keys packed) ----
    {
      int p = tid & 31, dh = tid >> 5;     // keypair, d-quarter
      const float* v0 = vb + (size_t)(b * cT + kt + 2 * p) * (cNKV * cHD) + kvh * cHD + dh * 16;
      const float* v1 = v0 + cNKV * cHD;
      f4 a0[4], a1[4];
      #pragma unroll
      for (int q = 0; q < 4; q++) { a0[q] = *(const f4*)(v0 + q * 4); a1[q] = *(const f4*)(v1 + q * 4); }
      #pragma unroll
      for (int j = 0; j < 16; j++) {
        int d = dh * 16 + j;
        unsigned pk = (unsigned)(unsigned short)f2bf(a0[j >> 2][j & 3])
                    | ((unsigned)(unsigned short)f2bf(a1[j >> 2][j & 3]) << 16);
        *(unsigned*)((char*)Vt + d * 128 + ((p * 4) ^ ((d & 7) << 4))) = pk;
      }
    }
    __syncthreads();

    // ---- QK^T: S[32q][64key] = 8 MFMA ----
    f16x s0 = {}, s1 = {};
    #pragma unroll
    for (int k = 0; k < 4; k++) {
      int o16 = k * 2 + g;
      sh8 b0 = *(sh8*)((char*)Kl + c * 128 + ((o16 ^ (c & 7)) * 16));
      sh8 b1 = *(sh8*)((char*)Kl + (32 + c) * 128 + ((o16 ^ ((32 + c) & 7)) * 16));
      s0 = __builtin_amdgcn_mfma_f32_32x32x16_bf16(aq[k], b0, s0, 0, 0, 0);
      s1 = __builtin_amdgcn_mfma_f32_32x32x16_bf16(aq[k], b1, s1, 0, 0, 0);
    }

    // ---- mask (diag tiles only; wave-uniform test) ----
    if (kt + 63 > qb0 + w * 32) {
      #pragma unroll
      for (int i = 0; i < 16; i++) {
        int r = qb0 + w * 32 + (i & 3) + 8 * (i >> 2) + 4 * g;
        if (kt + c > r)      s0[i] = -1e30f;
        if (kt + 32 + c > r) s1[i] = -1e30f;
      }
    }

    // ---- online softmax (rows spread: 16 regs/lane, reduce over 32 lanes) ----
    #pragma unroll
    for (int i = 0; i < 16; i++) {
      float mt = fmaxf(s0[i], s1[i]);
      #pragma unroll
      for (int off = 1; off < 32; off <<= 1) mt = fmaxf(mt, __shfl_xor(mt, off));
      float mn = fmaxf(m[i], mt);
      float rs = __expf(m[i] - mn);
      m[i] = mn;
      float p0 = __expf(s0[i] - mn);
      float p1 = __expf(s1[i] - mn);
      s0[i] = p0; s1[i] = p1;
      float ps = p0 + p1;
      #pragma unroll
      for (int off = 1; off < 32; off <<= 1) ps += __shfl_xor(ps, off);
      ll[i] = ll[i] * rs + ps;
      o0[i] *= rs; o1[i] *= rs;
    }

    // ---- P -> LDS (bf16, C-layout rows) ----
    #pragma unroll
    for (int i = 0; i < 16; i++) {
      int r = (i & 3) + 8 * (i >> 2) + 4 * g;
      *(short*)((char*)Pl[w] + r * 128 + ((c * 2) ^ ((r & 7) << 4)))        = f2bf(s0[i]);
      *(short*)((char*)Pl[w] + r * 128 + (((32 + c) * 2) ^ ((r & 7) << 4))) = f2bf(s1[i]);
    }

    // ---- PV: O[32q][64d] += P[32][64] x V[64][64] = 8 MFMA ----
    #pragma unroll
    for (int k = 0; k < 4; k++) {
      int o16 = k * 2 + g;
      sh8 ap  = *(sh8*)((char*)Pl[w] + c * 128 + ((o16 ^ (c & 7)) * 16));
      sh8 bv0 = *(sh8*)((char*)Vt + c * 128 + ((o16 ^ (c & 7)) * 16));
      sh8 bv1 = *(sh8*)((char*)Vt + (32 + c) * 128 + ((o16 ^ ((32 + c) & 7)) * 16));
      o0 = __builtin_amdgcn_mfma_f32_32x32x16_bf16(ap, bv0, o0, 0, 0, 0);
      o1 = __builtin_amdgcn_mfma_f32_32x32x16_bf16(ap, bv1, o1, 0, 0, 0);
    }
  }

  // ---- epilogue ----
  #pragma unroll
  for (int i = 0; i < 16; i++) {
    int r = qb0 + w * 32 + (i & 3) + 8 * (i >> 2) + 4 * g;
    float inv = 1.0f / ll[i];
    float* yp = yb + (size_t)(b * cT + r) * cC + h * cHD;
    yp[c]      = o0[i] * inv;
    yp[32 + c] = o1[i] * inv;
  }
}

// ---------------- gate: logits, top-2, softmax, atomic routing ----------------
__global__ __launch_bounds__(256) void gate_k(const float* __restrict__ h2,
                                              const float* __restrict__ gw,
                                              int* __restrict__ sel, float* __restrict__ selw,
                                              int* __restrict__ cnt, int* __restrict__ elist)
{
  int wv = threadIdx.x >> 6, lane = threadIdx.x & 63;
  int n = blockIdx.x * 4 + wv;
  float acc[8] = {0.f, 0.f, 0.f, 0.f, 0.f, 0.f, 0.f, 0.f};
  for (int c = lane; c < cC; c += 64) {
    float hv = h2[(size_t)n * cC + c];
    f4 g0 = *(const f4*)(gw + c * 8);
    f4 g1 = *(const f4*)(gw + c * 8 + 4);
    acc[0] = fmaf(hv, g0[0], acc[0]); acc[1] = fmaf(hv, g0[1], acc[1]);
    acc[2] = fmaf(hv, g0[2], acc[2]); acc[3] = fmaf(hv, g0[3], acc[3]);
    acc[4] = fmaf(hv, g1[0], acc[4]); acc[5] = fmaf(hv, g1[1], acc[5]);
    acc[6] = fmaf(hv, g1[2], acc[6]); acc[7] = fmaf(hv, g1[3], acc[7]);
  }
  #pragma unroll
  for (int e = 0; e < 8; e++)
    #pragma unroll
    for (int off = 32; off; off >>= 1) acc[e] += __shfl_xor(acc[e], off);
  if (lane == 0) {
    int i0 = 0; float m0 = acc[0];
    #pragma unroll
    for (int e = 1; e < 8; e++) if (acc[e] > m0) { m0 = acc[e]; i0 = e; }
    int i1 = -1; float m1 = -INFINITY;
    #pragma unroll
    for (int e = 0; e < 8; e++) if (e != i0 && acc[e] > m1) { m1 = acc[e]; i1 = e; }
    float e1 = expf(m1 - m0);
    float p0 = 1.f / (1.f + e1);
    float p1 = e1 / (1.f + e1);
    sel[n * 2] = i0;  selw[n * 2] = p0;
    sel[n * 2 + 1] = i1; selw[n * 2 + 1] = p1;
    int pos0 = atomicAdd(&cnt[i0], 1); elist[(size_t)i0 * cN + pos0] = n * 2;
    int pos1 = atomicAdd(&cnt[i1], 1); elist[(size_t)i1 * cN + pos1] = n * 2 + 1;
  }
}

// ---------------- weighted combine ----------------
__global__ void combine_k(float* __restrict__ x, const float* __restrict__ eo,
                          const float* __restrict__ selw)
{
  int n = blockIdx.x, tid = threadIdx.x;
  float w0 = selw[n * 2], w1 = selw[n * 2 + 1];
  f4 a = *(const f4*)(eo + (size_t)(n * 2) * cC + tid * 4);
  f4 b = *(const f4*)(eo + (size_t)(n * 2 + 1) * cC + tid * 4);
  f4 xv = *(f4*)(x + (size_t)n * cC + tid * 4);
  xv += a * w0 + b * w1;
  *(f4*)(x + (size_t)n * cC + tid * 4) = xv;
}

// ---------------- logits ----------------
__global__ __launch_bounds__(256) void logits_k(const float* __restrict__ hf,
                                                const float* __restrict__ wte,
                                                float* __restrict__ out)
{
  int wv = threadIdx.x >> 6, lane = threadIdx.x & 63;
  int v = blockIdx.x * 4 + wv;
  const float* wrow = wte + (size_t)v * cC;
  const float* r0 = hf + (size_t)(cT - 1) * cC;
  const float* r1 = hf + (size_t)(2 * cT - 1) * cC;
  float a0 = 0.f, a1 = 0.f;
  for (int c = lane * 4; c < cC; c += 256) {
    f4 w4 = *(const f4*)(wrow + c);
    f4 x0 = *(const f4*)(r0 + c);
    f4 x1 = *(const f4*)(r1 + c);
    a0 += dot4(w4, x0);
    a1 += dot4(w4, x1);
  }
  #pragma unroll
  for (int off = 32; off; off >>= 1) { a0 += __shfl_xor(a0, off); a1 += __shfl_xor(a1, off); }
  if (lane == 0) { out[v] = a0; out[cV + v] = a1; }
}

// =======================================================================
extern "C" void kernel_launch(void* const* d_in, const int* in_sizes, int n_in,
                              void* d_out, int out_size, void* d_ws, size_t ws_size,
                              hipStream_t stream)
{
  (void)in_sizes; (void)n_in; (void)out_size;
  const int*   idx  = (const int*)  d_in[0];
  const float* wte  = (const float*)d_in[1];
  const float* ln1w = (const float*)d_in[2];
  const float* p_wq = (const float*)d_in[3];
  const float* p_wk = (const float*)d_in[4];
  const float* p_wv = (const float*)d_in[5];
  const float* p_wo = (const float*)d_in[6];
  const float* ln2w = (const float*)d_in[7];
  const float* gw   = (const float*)d_in[8];
  const float* w1   = (const float*)d_in[9];
  const float* w2   = (const float*)d_in[10];
  const float* w3   = (const float*)d_in[11];
  const float* lnfw = (const float*)d_in[12];
  float* out = (float*)d_out;

  float* ws = (float*)d_ws;
  size_t o = 0;
  float* x    = ws + o; o += (size_t)cN * cC;
  float* h    = ws + o; o += (size_t)cN * cC;
  float* q    = ws + o; o += (size_t)cN * cC;
  float* kbuf = ws + o; o += (size_t)cN * cNKV * cHD;
  float* vbuf = ws + o; o += (size_t)cN * cNKV * cHD;
  float* y    = ws + o; o += (size_t)cN * cC;
  float* acts = ws + o; o += (size_t)cN * 2 * cHID;
  float* eo   = ws + o; o += (size_t)cN * 2 * cC;
  float* selw = ws + o; o += (size_t)cN * 2;
  int* sel    = (int*)(ws + o); o += (size_t)cN * 2;
  int* cnt    = (int*)(ws + o); o += 8;
  int* elist  = (int*)(ws + o); o += (size_t)cE * cN;
  if (ws_size < o * sizeof(float)) return;

  embed_k<<<cN, 256, 0, stream>>>(idx, wte, x);

  for (int l = 0; l < 2; l++) {
    // ---- attention ----
    rmsnorm_k<<<cN, 256, 0, stream>>>(x, ln1w + (size_t)l * cC, h);
    mgemm<0,0><<<dim3(8, 16), 256, 0, stream>>>(h, p_wq + (size_t)l * cC * 1024, q,
        cN, 1024, cC, cC, 1024, 1024, nullptr, nullptr);
    mgemm<0,0><<<dim3(4, 16), 256, 0, stream>>>(h, p_wk + (size_t)l * cC * 512, kbuf,
        cN, 512, cC, cC, 512, 512, nullptr, nullptr);
    mgemm<0,0><<<dim3(4, 16), 256, 0, stream>>>(h, p_wv + (size_t)l * cC * 512, vbuf,
        cN, 512, cC, cC, 512, 512, nullptr, nullptr);
    rope_k<<<(cN * cNH * 32) / 256, 256, 0, stream>>>(q, cNH);
    rope_k<<<(cN * cNKV * 32) / 256, 256, 0, stream>>>(kbuf, cNKV);
    attn_k<<<dim3(16, cNH, cB), 128, 0, stream>>>(q, kbuf, vbuf, y);
    mgemm<1,0><<<dim3(8, 16), 256, 0, stream>>>(y, p_wo + (size_t)l * 1024 * cC, x,
        cN, cC, 1024, 1024, cC, cC, nullptr, nullptr);   // x += y @ wo

    // ---- MoE ----
    rmsnorm_k<<<cN, 256, 0, stream>>>(x, ln2w + (size_t)l * cC, h);
    hipMemsetAsync(cnt, 0, cE * sizeof(int), stream);
    gate_k<<<cN / 4, 256, 0, stream>>>(h, gw + (size_t)l * cC * cE, sel, selw, cnt, elist);
    mgemm<2,1><<<dim3(22, 16, 8), 256, 0, stream>>>(h, w1 + (size_t)l * cE * cC * cHID, acts,
        0, cHID, cC, cC, cHID, cHID, elist, cnt);
    mgemm<3,1><<<dim3(22, 16, 8), 256, 0, stream>>>(h, w3 + (size_t)l * cE * cC * cHID, acts,
        0, cHID, cC, cC, cHID, cHID, elist, cnt);
    mgemm<0,2><<<dim3(8, 16, 8), 256, 0, stream>>>(acts, w2 + (size_t)l * cE * cHID * cC, eo,
        0, cC, cHID, cHID, cC, cC, elist, cnt);
    combine_k<<<cN, 256, 0, stream>>>(x, eo, selw);
  }

  rmsnorm_k<<<cN, 256, 0, stream>>>(x, lnfw, h);
  logits_k<<<cV / 4, 256, 0, stream>>>(h, wte, out);
}